// Round 10
// baseline (140.524 us; speedup 1.0000x reference)
//
#include <hip/hip_runtime.h>
#include <hip/hip_bf16.h>

typedef short bf16x8 __attribute__((ext_vector_type(8)));
typedef float f32x4 __attribute__((ext_vector_type(4)));
typedef unsigned short u16x4 __attribute__((ext_vector_type(4)));
typedef unsigned int u32x4 __attribute__((ext_vector_type(4)));

#define B_ 16
#define T_ 2048
#define C_ 1024
#define D_ 128
#define M_ (B_ * T_)

static __device__ __forceinline__ unsigned short f2bf(float f) {
    unsigned int u = __builtin_bit_cast(unsigned int, f);
    unsigned int r = (u + 0x7fffu + ((u >> 16) & 1u)) >> 16;
    return (unsigned short)r;
}

// async global->LDS, 16B per lane; LDS dest = wave-uniform base + lane*16
static __device__ __forceinline__ void gll16(const void* g, void* l) {
    __builtin_amdgcn_global_load_lds(
        (const __attribute__((address_space(1))) void*)g,
        (__attribute__((address_space(3))) void*)l, 16, 0, 0);
}

// pack 2 f32 -> 1 dword of 2 bf16 (hardware round)
static __device__ __forceinline__ unsigned int cvtpk(float lo, float hi) {
    unsigned int r;
    asm("v_cvt_pk_bf16_f32 %0, %1, %2" : "=v"(r) : "v"(lo), "v"(hi));
    return r;
}

// ---------------------------------------------------------------------------
// Kernel 0: W [1024k][128n] fp32 (x3) -> Wt [384n][1024k] bf16 with k-granule
// (8 shorts = 16B) swizzle baked:  stored granule G^(n&7) holds logical G.
// ---------------------------------------------------------------------------
#define TPAD 133

__global__ void wt_kernel(const float* __restrict__ Wq, const float* __restrict__ Wk,
                          const float* __restrict__ Wv, unsigned short* __restrict__ Wt) {
    __shared__ float Tl[64 * TPAD];
    const int o  = blockIdx.x >> 4;    // 0..2
    const int k0 = (blockIdx.x & 15) * 64;
    const float* W = (o == 0) ? Wq : (o == 1) ? Wk : Wv;
    const int tid = threadIdx.x;

    const int kr = tid >> 5;           // 0..7 (+j*8)
    const int n4 = (tid & 31) * 4;
#pragma unroll
    for (int j = 0; j < 8; ++j) {
        float4 v = *(const float4*)(W + (size_t)(k0 + kr + j * 8) * 128 + n4);
        *(float4*)&Tl[(kr + j * 8) * TPAD + n4] = v;
    }
    __syncthreads();

    const int nb = tid >> 3;           // 0..31 (+j*32)
    const int kg = (tid & 7) * 8;      // stored-position granule (shorts)
#pragma unroll
    for (int j = 0; j < 4; ++j) {
        const int nn = nb + j * 32;
        const int kk = kg ^ ((nn & 7) * 8);   // logical k granule
        bf16x8 v;
#pragma unroll
        for (int e = 0; e < 8; ++e)
            v[e] = (short)f2bf(Tl[(kk + e) * TPAD + nn]);
        *(bf16x8*)&Wt[((size_t)o * 128 + nn) * 1024 + k0 + kg] = v;
    }
}

// ---------------------------------------------------------------------------
// Kernel 1: fused QKV GEMM — T3 2-phase + T4 counted vmcnt (raw barriers).
// BM=64, BN=128, BK=64. 256 thr / 4 waves (2x2), per-wave 32x64 (2x4 frags).
// A staged as RAW FP32 via gll (swizzle applied at per-lane global source,
// m173); B bf16 via gll (swizzle baked in Wt). Double-buffered, 64 KB LDS,
// 2 blocks/CU. Per step, per wave, exactly 8 gll:
//   vmcnt(8)[tile t landed, t+1 in flight] -> s_barrier -> compute(t)
//   -> s_barrier -> stage(t+2).
// No __syncthreads in the loop: loads stay in flight across barriers.
// fp32->bf16 conversion fused into compute via v_cvt_pk_bf16_f32.
// grid = 1536: nt = bid>>9 (0=Q,1=K,2=Vt), mt = bid&511; nt-generations
// re-read x from L3 (128 MB < 256 MB).
// ---------------------------------------------------------------------------
__launch_bounds__(256, 2)
__global__ void qkv_kernel(const float* __restrict__ x, const unsigned short* __restrict__ Wt,
                           unsigned short* __restrict__ Q, unsigned short* __restrict__ K,
                           unsigned short* __restrict__ Vt) {
    __shared__ float          Af[2][64 * 64];    // 2 x 16 KB (fp32 A tile)
    __shared__ unsigned short Bs[2][128 * 64];   // 2 x 16 KB (bf16 B tile)

    const int tid  = threadIdx.x;
    const int lane = tid & 63;
    const int w    = tid >> 6;   // 0..3
    const int wr   = w >> 1;     // 0..1 (32-row group)
    const int wc   = w & 1;      // 0..1 (64-col group)
    const int lr   = lane & 15;
    const int lk   = lane >> 4;  // 0..3

    const int nt = blockIdx.x >> 9;         // 0..2 (Q/K/V)
    const int mt = blockIdx.x & 511;
    const int m0 = mt * 64;
    const int n0 = nt * 128;

    // A: 16 calls/block (4/wave); call = 4 rows x 16 granules of 4 floats.
    // global src granule pre-swizzled: g' = g ^ (row&7)  (inverse == itself)
    auto stageA = [&](int buf, int t) {
        const int k0 = t * 64;
#pragma unroll
        for (int j = 0; j < 4; ++j) {
            const int R   = w * 16 + j * 4;
            const int row = R + (lane >> 4);          // 4 rows per call
            const int g   = lane & 15;
            gll16(x + (size_t)(m0 + row) * C_ + k0 + ((g ^ (row & 7)) << 2),
                  &Af[buf][R * 64]);
        }
    };
    // B: 16 calls/block (4/wave); call = 8 rows x 8 granules of 8 shorts.
    // Wt already stores the swizzled layout -> linear copy.
    auto stageB = [&](int buf, int t) {
        const int k0 = t * 64;
#pragma unroll
        for (int j = 0; j < 4; ++j) {
            const int R   = w * 32 + j * 8;
            const int row = R + (lane >> 3);
            const int g   = lane & 7;
            gll16(Wt + (size_t)(n0 + row) * 1024 + k0 + g * 8,
                  &Bs[buf][R * 64]);
        }
    };

    f32x4 acc[2][4] = {};

    auto compute = [&](int buf) {
#pragma unroll
        for (int kk = 0; kk < 2; ++kk) {
            bf16x8 a[2], b[4];
#pragma unroll
            for (int rb = 0; rb < 2; ++rb) {
                const int row = wr * 32 + rb * 16 + lr;
                const int s   = row & 7;
                const int g0  = kk * 8 + lk * 2;      // fp32 granule (4 floats)
                float4 f0 = *(const float4*)&Af[buf][row * 64 + ((g0 ^ s) << 2)];
                float4 f1 = *(const float4*)&Af[buf][row * 64 + (((g0 + 1) ^ s) << 2)];
                u32x4 pk;
                pk[0] = cvtpk(f0.x, f0.y); pk[1] = cvtpk(f0.z, f0.w);
                pk[2] = cvtpk(f1.x, f1.y); pk[3] = cvtpk(f1.z, f1.w);
                a[rb] = __builtin_bit_cast(bf16x8, pk);
            }
#pragma unroll
            for (int nb = 0; nb < 4; ++nb) {
                const int row = wc * 64 + nb * 16 + lr;
                const int gb  = (kk * 4 + lk) ^ (row & 7);   // bf16 granule (8 shorts)
                b[nb] = *(const bf16x8*)&Bs[buf][row * 64 + gb * 8];
            }
#pragma unroll
            for (int rb = 0; rb < 2; ++rb)
#pragma unroll
                for (int nb = 0; nb < 4; ++nb)
                    acc[rb][nb] = __builtin_amdgcn_mfma_f32_16x16x32_bf16(a[rb], b[nb], acc[rb][nb], 0, 0, 0);
        }
    };

    // prologue: 2 tiles in flight (16 gll outstanding per wave)
    stageA(0, 0); stageB(0, 0);
    stageA(1, 1); stageB(1, 1);

    for (int t = 0; t < 16; ++t) {
        if (t < 15) asm volatile("s_waitcnt vmcnt(8)" ::: "memory");   // tile t landed
        else        asm volatile("s_waitcnt vmcnt(0)" ::: "memory");   // last tile
        __builtin_amdgcn_s_barrier();        // all waves' tile-t gll visible
        compute(t & 1);
        __builtin_amdgcn_s_barrier();        // all waves done reading buf[t&1]
        if (t < 14) { stageA(t & 1, t + 2); stageB(t & 1, t + 2); }
    }

    // epilogue. D frag layout: row = lk*4 + r, col = lr
    const float qscale = 0.08838834764831845f;
    const int b  = m0 / T_;
    const int t0 = m0 % T_;
#pragma unroll
    for (int rb = 0; rb < 2; ++rb) {
#pragma unroll
        for (int nb = 0; nb < 4; ++nb) {
            const int row0 = wr * 32 + rb * 16 + lk * 4;
            const int d    = wc * 64 + nb * 16 + lr;
            f32x4 a = acc[rb][nb];
            if (nt == 0) {
#pragma unroll
                for (int r = 0; r < 4; ++r)
                    Q[(size_t)(m0 + row0 + r) * D_ + d] = f2bf(a[r] * qscale);
            } else if (nt == 1) {
#pragma unroll
                for (int r = 0; r < 4; ++r)
                    K[(size_t)(m0 + row0 + r) * D_ + d] = f2bf(a[r]);
            } else {
                u16x4 pv;
#pragma unroll
                for (int r = 0; r < 4; ++r) pv[r] = f2bf(a[r]);
                *(u16x4*)&Vt[((size_t)b * D_ + d) * T_ + t0 + row0] = pv;
            }
        }
    }
}

// ---------------------------------------------------------------------------
// Kernel 2: causal flash attention (unchanged — passed R4-R9). XCD-pinned
// remap: batches 2x,2x+1 on XCD x; short/long q-tiles pair per CU.
// ---------------------------------------------------------------------------
#define KSTR 132   // 128 + 4
#define VSTR 68    // 64 + 4
#define PSTR 68

__launch_bounds__(256, 2)
__global__ void attn_kernel(const unsigned short* __restrict__ Q, const unsigned short* __restrict__ K,
                            const unsigned short* __restrict__ Vt, float* __restrict__ out) {
    __shared__ unsigned short Klds[2][64 * KSTR];
    __shared__ unsigned short Vlds[2][128 * VSTR];
    __shared__ unsigned short Plds[4][16 * PSTR];

    const int tid  = threadIdx.x;
    const int lane = tid & 63;
    const int w    = tid >> 6;
    const int lr   = lane & 15;
    const int lk   = lane >> 4;

    const int xcd = blockIdx.x & 7;
    const int p   = blockIdx.x >> 3;
    const int batch = xcd * 2 + (p & 1);
    const int q     = p >> 1;
    const int qt    = (q < 16) ? q : (47 - q);

    const unsigned short* Qb = Q  + (size_t)batch * T_ * D_;
    const unsigned short* Kb = K  + (size_t)batch * T_ * D_;
    const unsigned short* Vb = Vt + (size_t)batch * D_ * T_;
    float* outb = out + (size_t)batch * T_ * D_;

    const int kxr = tid >> 4;
    const int kxc = (tid & 15) * 8;
    const int vxr = tid >> 3;
    const int vxc = (tid & 7) * 8;

    bf16x8 kr[4], vr[4];
    auto kv_load = [&](int kvt) {
        const int kv0 = kvt * 64;
#pragma unroll
        for (int j = 0; j < 4; ++j)
            kr[j] = *(const bf16x8*)(Kb + (size_t)(kv0 + kxr + j * 16) * D_ + kxc);
#pragma unroll
        for (int j = 0; j < 4; ++j)
            vr[j] = *(const bf16x8*)(Vb + (size_t)(vxr + j * 32) * T_ + kv0 + vxc);
    };
    auto kv_write = [&](int buf) {
#pragma unroll
        for (int j = 0; j < 4; ++j)
            *(bf16x8*)&Klds[buf][(kxr + j * 16) * KSTR + kxc] = kr[j];
#pragma unroll
        for (int j = 0; j < 4; ++j)
            *(bf16x8*)&Vlds[buf][(vxr + j * 32) * VSTR + vxc] = vr[j];
    };

    const int qw = qt * 64 + w * 16;

    bf16x8 qf[4];
#pragma unroll
    for (int c = 0; c < 4; ++c)
        qf[c] = *(const bf16x8*)(Qb + (size_t)(qw + lr) * D_ + lk * 8 + c * 32);

    f32x4 o_acc[8] = {};
    float mrun[4] = {-1e30f, -1e30f, -1e30f, -1e30f};
    float lrun[4] = {0.f, 0.f, 0.f, 0.f};

    kv_load(0);
    kv_write(0);

    for (int kvt = 0; kvt <= qt; ++kvt) {
        const int cur = kvt & 1;
        __syncthreads();
        if (kvt < qt) kv_load(kvt + 1);

        f32x4 s[4];
#pragma unroll
        for (int nb = 0; nb < 4; ++nb) {
            f32x4 a = {};
#pragma unroll
            for (int c = 0; c < 4; ++c) {
                bf16x8 kf = *(bf16x8*)&Klds[cur][(nb * 16 + lr) * KSTR + lk * 8 + c * 32];
                a = __builtin_amdgcn_mfma_f32_16x16x32_bf16(qf[c], kf, a, 0, 0, 0);
            }
            s[nb] = a;
        }

        if (kvt == qt) {
#pragma unroll
            for (int nb = 0; nb < 4; ++nb)
#pragma unroll
                for (int r = 0; r < 4; ++r) {
                    int qg = qw + lk * 4 + r;
                    int kg = kvt * 64 + nb * 16 + lr;
                    if (kg > qg) s[nb][r] = -1e30f;
                }
        }

        float scale_[4];
#pragma unroll
        for (int r = 0; r < 4; ++r) {
            float mx = fmaxf(fmaxf(s[0][r], s[1][r]), fmaxf(s[2][r], s[3][r]));
            mx = fmaxf(mx, __shfl_xor(mx, 1));
            mx = fmaxf(mx, __shfl_xor(mx, 2));
            mx = fmaxf(mx, __shfl_xor(mx, 4));
            mx = fmaxf(mx, __shfl_xor(mx, 8));
            float mnew = fmaxf(mrun[r], mx);
            scale_[r]  = __expf(mrun[r] - mnew);
            mrun[r]    = mnew;
            lrun[r]   *= scale_[r];
        }
#pragma unroll
        for (int db = 0; db < 8; ++db)
#pragma unroll
            for (int r = 0; r < 4; ++r) o_acc[db][r] *= scale_[r];

#pragma unroll
        for (int nb = 0; nb < 4; ++nb)
#pragma unroll
            for (int r = 0; r < 4; ++r) {
                float p_ = __expf(s[nb][r] - mrun[r]);
                lrun[r] += p_;
                Plds[w][(lk * 4 + r) * PSTR + nb * 16 + lr] = f2bf(p_);
            }
        asm volatile("s_waitcnt lgkmcnt(0)" ::: "memory");
        __builtin_amdgcn_sched_barrier(0);

        bf16x8 pa[2];
#pragma unroll
        for (int c = 0; c < 2; ++c)
            pa[c] = *(bf16x8*)&Plds[w][lr * PSTR + lk * 8 + c * 32];
#pragma unroll
        for (int db = 0; db < 8; ++db) {
            f32x4 oo = o_acc[db];
#pragma unroll
            for (int c = 0; c < 2; ++c) {
                bf16x8 vf = *(bf16x8*)&Vlds[cur][(db * 16 + lr) * VSTR + lk * 8 + c * 32];
                oo = __builtin_amdgcn_mfma_f32_16x16x32_bf16(pa[c], vf, oo, 0, 0, 0);
            }
            o_acc[db] = oo;
        }

        if (kvt < qt) kv_write(cur ^ 1);
    }

#pragma unroll
    for (int r = 0; r < 4; ++r) {
        float sgm = lrun[r];
        sgm += __shfl_xor(sgm, 1);
        sgm += __shfl_xor(sgm, 2);
        sgm += __shfl_xor(sgm, 4);
        sgm += __shfl_xor(sgm, 8);
        lrun[r] = 1.0f / sgm;
    }
#pragma unroll
    for (int db = 0; db < 8; ++db)
#pragma unroll
        for (int r = 0; r < 4; ++r)
            outb[(size_t)(qw + lk * 4 + r) * D_ + db * 16 + lr] = o_acc[db][r] * lrun[r];
}

// ---------------------------------------------------------------------------
extern "C" void kernel_launch(void* const* d_in, const int* in_sizes, int n_in,
                              void* d_out, int out_size, void* d_ws, size_t ws_size,
                              hipStream_t stream) {
    const float* x  = (const float*)d_in[0];
    const float* Wq = (const float*)d_in[1];
    const float* Wk = (const float*)d_in[2];
    const float* Wv = (const float*)d_in[3];

    unsigned short* Wt  = (unsigned short*)d_ws;                          // 768 KB
    unsigned short* Qw  = (unsigned short*)((char*)d_ws + (1 << 20));     // 8 MB
    unsigned short* Kw  = Qw + (size_t)M_ * D_;                           // 8 MB
    unsigned short* Vtw = Kw + (size_t)M_ * D_;                           // 8 MB

    hipLaunchKernelGGL(wt_kernel, dim3(48), dim3(256), 0, stream, Wq, Wk, Wv, Wt);
    hipLaunchKernelGGL(qkv_kernel, dim3(1536), dim3(256), 0, stream, x, Wt, Qw, Kw, Vtw);
    hipLaunchKernelGGL(attn_kernel, dim3(512), dim3(256), 0, stream, Qw, Kw, Vtw, (float*)d_out);
}